// Round 1
// baseline (133.117 us; speedup 1.0000x reference)
//
#include <hip/hip_runtime.h>
#include <stdint.h>

// Problem constants
#define D_    64
#define NVOX  4096     // X*Y*Z = 16*16*16
#define NROWS 16384    // B*NVOX
#define K_    8192

// GEMM tiling
#define MT      128                // rows per block
#define KC      128                // codebook entries per chunk
#define KSPLIT  8
#define KSEC    (K_ / KSPLIT)      // 1024
#define NCHUNK  (KSEC / KC)        // 8
#define LDA     72                 // LDS row stride in shorts (64 + 8 pad -> 36 dwords, 2-way max)

typedef __attribute__((ext_vector_type(8))) short short8;
typedef __attribute__((ext_vector_type(4))) float f32x4;

__device__ __forceinline__ unsigned short f2bf(float f) {
  union { float f; unsigned u; } v; v.f = f;
  unsigned r = v.u + 0x7FFFu + ((v.u >> 16) & 1u);  // RNE
  return (unsigned short)(r >> 16);
}

// ---------------------------------------------------------------------------
// Kernel 1: codebook fp32 -> bf16, scaled norms (norm2 = 0.75 + 32*||e||^2),
// init run[] = 0xFFFFFFFF, zero loss accumulator + completion counter.
// 128 blocks x 256 threads; 64 codebook rows per block (4 threads/row).
// ---------------------------------------------------------------------------
__global__ __launch_bounds__(256) void vq_prep(
    const float* __restrict__ cb,
    unsigned* __restrict__ cbb,     // [K_*32] uints (bf16x2 packed)
    float* __restrict__ norm2,      // [K_]
    unsigned* __restrict__ run,     // [NROWS]
    float* __restrict__ misc)       // [0]=loss sum, [1]=counter (as uint)
{
  const int t = threadIdx.x, blk = blockIdx.x;
  const int row = blk * 64 + (t >> 2);
  const int cg  = (t & 3) * 16;
  const float* src = cb + row * 64 + cg;
  float ss = 0.f;
  unsigned ou[8];
#pragma unroll
  for (int i = 0; i < 4; ++i) {
    float4 v = ((const float4*)src)[i];
    ss += v.x * v.x + v.y * v.y + v.z * v.z + v.w * v.w;
    ou[i * 2]     = (unsigned)f2bf(v.x) | ((unsigned)f2bf(v.y) << 16);
    ou[i * 2 + 1] = (unsigned)f2bf(v.z) | ((unsigned)f2bf(v.w) << 16);
  }
  ss += __shfl_xor(ss, 1);
  ss += __shfl_xor(ss, 2);
  unsigned* dst = cbb + row * 32 + (t & 3) * 8;
  ((uint4*)dst)[0] = make_uint4(ou[0], ou[1], ou[2], ou[3]);
  ((uint4*)dst)[1] = make_uint4(ou[4], ou[5], ou[6], ou[7]);
  if ((t & 3) == 0) norm2[row] = 0.75f + 32.f * ss;

  if (t < 128) run[blk * 128 + t] = 0xFFFFFFFFu;
  if (blk == 0 && t == 0) misc[0] = 0.f;
  if (blk == 0 && t == 1) ((unsigned*)misc)[1] = 0u;
}

// ---------------------------------------------------------------------------
// Kernel 2: MFMA GEMM (A = transposed latents, B^T = codebook) with fused
// packed-argmin epilogue. Grid = 128 m-blocks x KSPLIT = 1024 blocks,
// 256 threads (4 waves, 32 rows each as 2 m-tiles of 16).
// ---------------------------------------------------------------------------
__global__ __launch_bounds__(256, 4) void vq_gemm(
    const float* __restrict__ lat,      // [4,64,4096]
    const unsigned* __restrict__ cbb,   // bf16x2
    const float* __restrict__ norm2,
    unsigned* __restrict__ run)
{
  __shared__ __align__(16) short lA[MT * LDA];   // 18432 B
  __shared__ __align__(16) short lB[KC * LDA];   // 18432 B
  __shared__ float lN[KC];

  const int t = threadIdx.x;
  const int bm = blockIdx.x & 127;
  const int ks = blockIdx.x >> 7;
  const int row0 = bm * MT;
  const int b = row0 >> 12;
  const int xyz0 = row0 & 4095;

  // Stage + transpose-convert A tile: 128 rows x 64 d (reads coalesced over xyz)
  {
    const float* base = lat + ((size_t)b * 64) * 4096 + xyz0;
#pragma unroll
    for (int i = 0; i < 32; ++i) {
      int e = i * 256 + t;
      int d = e >> 7, r = e & 127;
      lA[r * LDA + d] = (short)f2bf(base[d * 4096 + r]);
    }
  }
  __syncthreads();

  const int lane = t & 63, wid = t >> 6;
  const int l15 = lane & 15, q = lane >> 4;

  // A fragments: 2 m-tiles x 2 k-steps, invariant across chunks
  short8 afr[2][2];
#pragma unroll
  for (int mt = 0; mt < 2; ++mt)
#pragma unroll
    for (int kk = 0; kk < 2; ++kk)
      afr[mt][kk] = *(const short8*)&lA[(wid * 32 + mt * 16 + l15) * LDA + q * 8 + kk * 32];

  unsigned rmin[2][4];
#pragma unroll
  for (int mt = 0; mt < 2; ++mt)
#pragma unroll
    for (int r = 0; r < 4; ++r) rmin[mt][r] = 0xFFFFFFFFu;

  for (int c = 0; c < NCHUNK; ++c) {
    const int kbase = ks * KSEC + c * KC;
    __syncthreads();
    // stage codebook chunk: 128 rows x 64 bf16 = 1024 uint4
    {
      const uint4* g = (const uint4*)(cbb + (size_t)kbase * 32);
#pragma unroll
      for (int i = 0; i < 4; ++i) {
        int e4 = i * 256 + t;
        uint4 v = g[e4];
        int r = e4 >> 3, c4 = e4 & 7;
        *(uint4*)&lB[r * LDA + c4 * 8] = v;
      }
      if (t < 32) ((float4*)lN)[t] = ((const float4*)(norm2 + kbase))[t];
    }
    __syncthreads();

#pragma unroll
    for (int nt = 0; nt < 8; ++nt) {
      short8 b0 = *(const short8*)&lB[(nt * 16 + l15) * LDA + q * 8];
      short8 b1 = *(const short8*)&lB[(nt * 16 + l15) * LDA + q * 8 + 32];
      float n2 = lN[nt * 16 + l15];
      unsigned kv = (unsigned)(kbase + nt * 16 + l15);
#pragma unroll
      for (int mt = 0; mt < 2; ++mt) {
        f32x4 acc = {0.f, 0.f, 0.f, 0.f};
        acc = __builtin_amdgcn_mfma_f32_16x16x32_bf16(afr[mt][0], b0, acc, 0, 0, 0);
        acc = __builtin_amdgcn_mfma_f32_16x16x32_bf16(afr[mt][1], b1, acc, 0, 0, 0);
#pragma unroll
        for (int r = 0; r < 4; ++r) {
          // score = norm - 2*dot, affine-mapped to (0.5,1): s = (0.75+32*norm) - 64*acc
          float s = fmaf(acc[r], -64.f, n2);
          unsigned p = (__float_as_uint(s) & 0xFFFFE000u) | kv;
          rmin[mt][r] = p < rmin[mt][r] ? p : rmin[mt][r];
        }
      }
    }
  }

  // reduce over the 16 lanes sharing each C-row (xor 1,2,4,8 stays in-quad)
#pragma unroll
  for (int mt = 0; mt < 2; ++mt)
#pragma unroll
    for (int r = 0; r < 4; ++r) {
      unsigned v = rmin[mt][r];
      unsigned o;
      o = (unsigned)__shfl_xor((int)v, 1); v = o < v ? o : v;
      o = (unsigned)__shfl_xor((int)v, 2); v = o < v ? o : v;
      o = (unsigned)__shfl_xor((int)v, 4); v = o < v ? o : v;
      o = (unsigned)__shfl_xor((int)v, 8); v = o < v ? o : v;
      rmin[mt][r] = v;
    }
  if (l15 == 0) {
#pragma unroll
    for (int mt = 0; mt < 2; ++mt)
#pragma unroll
      for (int r = 0; r < 4; ++r)
        atomicMin(&run[row0 + wid * 32 + mt * 16 + q * 4 + r], rmin[mt][r]);
  }
}

// ---------------------------------------------------------------------------
// Kernel 3: gather codebook rows into output layout + fused vq_loss.
// 1024 blocks x 256 threads, 4 elements (consecutive xyz) per thread.
// ---------------------------------------------------------------------------
__global__ __launch_bounds__(256) void vq_gather_loss(
    const float* __restrict__ lat,
    const float* __restrict__ vqw,
    const float* __restrict__ cb,
    const unsigned* __restrict__ run,
    float* __restrict__ out,
    float* __restrict__ misc)
{
  const int t = threadIdx.x;
  const int gid = blockIdx.x * 256 + t;
  const int E0 = gid * 4;
  const int xyz = E0 & 4095;
  const int d = (E0 >> 12) & 63;
  const int b = E0 >> 18;
  const int n0 = b * 4096 + xyz;

  float4 l4 = *(const float4*)(lat + E0);
  uint4 i4 = *(const uint4*)(run + n0);
  float q0 = cb[(i4.x & 8191u) * 64 + d];
  float q1 = cb[(i4.y & 8191u) * 64 + d];
  float q2 = cb[(i4.z & 8191u) * 64 + d];
  float q3 = cb[(i4.w & 8191u) * 64 + d];
  *(float4*)(out + E0) = make_float4(q0, q1, q2, q3);

  float d0 = q0 - l4.x, d1 = q1 - l4.y, d2 = q2 - l4.z, d3 = q3 - l4.w;
  float dsum = d0 * d0 + d1 * d1 + d2 * d2 + d3 * d3;
#pragma unroll
  for (int m = 1; m < 64; m <<= 1) dsum += __shfl_xor(dsum, m);

  __shared__ float wsum[4];
  const int lane = t & 63, wid = t >> 6;
  if (lane == 0) wsum[wid] = dsum;
  __syncthreads();
  if (t == 0) {
    float bs = wsum[0] + wsum[1] + wsum[2] + wsum[3];
    atomicAdd(misc, bs);
    __threadfence();
    unsigned old = atomicAdd((unsigned*)(misc + 1), 1u);
    if (old == (unsigned)(gridDim.x - 1)) {
      float total = atomicAdd(misc, 0.f);  // coherent device-scope read
      out[NROWS * 64] = total * (1.f + vqw[0]) / (float)(NROWS * 64);
    }
  }
}

// ---------------------------------------------------------------------------
extern "C" void kernel_launch(void* const* d_in, const int* in_sizes, int n_in,
                              void* d_out, int out_size, void* d_ws, size_t ws_size,
                              hipStream_t stream) {
  const float* lat = (const float*)d_in[0];
  const float* vqw = (const float*)d_in[1];
  const float* cb  = (const float*)d_in[2];
  float* out = (float*)d_out;

  unsigned* ws    = (unsigned*)d_ws;
  unsigned* cbb   = ws;                              // 262144 uints (1 MB)
  float*    norm2 = (float*)(ws + 262144);           // 8192 floats
  unsigned* run   = ws + 262144 + 8192;              // 16384 uints
  float*    misc  = (float*)(ws + 262144 + 8192 + 16384);  // 2 slots

  vq_prep<<<128, 256, 0, stream>>>(cb, cbb, norm2, run, misc);
  vq_gemm<<<128 * KSPLIT, 256, 0, stream>>>(lat, cbb, norm2, run);
  vq_gather_loss<<<1024, 256, 0, stream>>>(lat, vqw, cb, run, out, misc);
}

// Round 2
// 100.229 us; speedup vs baseline: 1.3281x; 1.3281x over previous
//
#include <hip/hip_runtime.h>
#include <stdint.h>

// Problem constants
#define D_    64
#define NROWS 16384    // B*X*Y*Z
#define K_    8192

// GEMM tiling
#define MT      128                // rows per block
#define KC      128                // codebook entries per chunk
#define KSPLIT  8
#define KSEC    (K_ / KSPLIT)      // 1024
#define NCHUNK  (KSEC / KC)        // 8
#define LDA     72                 // lA row stride in shorts (36 dwords; frag reads 2-way max)

typedef __attribute__((ext_vector_type(8))) short short8;
typedef __attribute__((ext_vector_type(4))) float f32x4;

__device__ __forceinline__ unsigned f2bf(float f) {
  union { float f; unsigned u; } v; v.f = f;
  unsigned r = v.u + 0x7FFFu + ((v.u >> 16) & 1u);  // RNE
  return r >> 16;
}

// async global->LDS, 16B per lane. lds = wave-uniform base; each lane lands at base + lane*16.
__device__ __forceinline__ void async_ld16(void* lds, const void* g) {
  __builtin_amdgcn_global_load_lds(
      (const __attribute__((address_space(1))) unsigned int*)g,
      (__attribute__((address_space(3))) unsigned int*)lds, 16, 0, 0);
}

// ---------------------------------------------------------------------------
// Kernel 1: codebook fp32 -> bf16 (XOR-swizzled atom layout for global_load_lds
// staging), scaled norms (0.75 + 32*||e||^2), init run[]=~0.
// 256 blocks x 256 threads; 32 codebook rows per block (8 threads/row).
// Swizzle: row r's 16B-atom j stored at global atom index r*8 + (j ^ (r&7)).
// ---------------------------------------------------------------------------
__global__ __launch_bounds__(256) void vq_prep(
    const float* __restrict__ cb,
    uint4* __restrict__ cbb16,      // [K_*8] swizzled bf16 atoms
    float* __restrict__ norm2,      // [K_]
    unsigned* __restrict__ run)     // [NROWS]
{
  const int t = threadIdx.x, blk = blockIdx.x;
  const int row = blk * 32 + (t >> 3);
  const int j = t & 7;
  const float4* src = (const float4*)(cb + row * 64 + j * 8);
  float4 v0 = src[0], v1 = src[1];
  float ss = v0.x * v0.x + v0.y * v0.y + v0.z * v0.z + v0.w * v0.w
           + v1.x * v1.x + v1.y * v1.y + v1.z * v1.z + v1.w * v1.w;
  uint4 o;
  o.x = f2bf(v0.x) | (f2bf(v0.y) << 16);
  o.y = f2bf(v0.z) | (f2bf(v0.w) << 16);
  o.z = f2bf(v1.x) | (f2bf(v1.y) << 16);
  o.w = f2bf(v1.z) | (f2bf(v1.w) << 16);
  ss += __shfl_xor(ss, 1);
  ss += __shfl_xor(ss, 2);
  ss += __shfl_xor(ss, 4);
  cbb16[row * 8 + (j ^ (row & 7))] = o;
  if (j == 0) norm2[row] = 0.75f + 32.f * ss;
  if (t < 64) run[blk * 64 + t] = 0xFFFFFFFFu;
}

// ---------------------------------------------------------------------------
// Kernel 2: MFMA GEMM (A = transposed latents, B^T = codebook) with fused
// packed-argmin epilogue. Grid = 128 m-blocks x KSPLIT = 1024 blocks,
// 256 threads (4 waves, 32 m-rows each as 2 m-tiles of 16).
// B staged via global_load_lds(16B) into swizzled LDS (conflict-free reads).
// ---------------------------------------------------------------------------
__global__ __launch_bounds__(256, 4) void vq_gemm(
    const float* __restrict__ lat,      // [4,64,4096]
    const uint4* __restrict__ cbb16,    // swizzled bf16 atoms
    const float* __restrict__ norm2,
    unsigned* __restrict__ run)
{
  __shared__ __align__(16) short lA[MT * LDA];   // 18432 B
  __shared__ __align__(16) char  lB[KC * 128];   // 16384 B (swizzled atoms)
  __shared__ float lN[KC];

  const int t = threadIdx.x;
  const int bm = blockIdx.x & 127;
  const int ks = blockIdx.x >> 7;
  const int row0 = bm * MT;
  const int b = row0 >> 12;
  const int xyz0 = row0 & 4095;

  // Stage + transpose-convert A tile: 128 rows x 64 d. Global reads coalesced
  // over xyz (lane<->r); packed bf16x2 ds_write_b32 (8-way conflict, once/block).
  {
    const float* base = lat + ((size_t)b * 64) * 4096 + xyz0;
    unsigned* lA32 = (unsigned*)lA;
#pragma unroll
    for (int i = 0; i < 16; ++i) {
      int e = i * 256 + t;
      int r = e & 127, dp = e >> 7;          // dp = d-pair index, 0..31
      float lo = base[(2 * dp) * 4096 + r];
      float hi = base[(2 * dp + 1) * 4096 + r];
      lA32[r * 36 + dp] = f2bf(lo) | (f2bf(hi) << 16);
    }
  }
  __syncthreads();

  const int lane = t & 63, wid = t >> 6;
  const int l15 = lane & 15, q = lane >> 4;

  // A fragments: 2 m-tiles x 2 k-steps, invariant across chunks
  short8 afr[2][2];
#pragma unroll
  for (int mt = 0; mt < 2; ++mt)
#pragma unroll
    for (int kk = 0; kk < 2; ++kk)
      afr[mt][kk] = *(const short8*)&lA[(wid * 32 + mt * 16 + l15) * LDA + q * 8 + kk * 32];

  unsigned rmin[2][4];
#pragma unroll
  for (int mt = 0; mt < 2; ++mt)
#pragma unroll
    for (int r = 0; r < 4; ++r) rmin[mt][r] = 0xFFFFFFFFu;

  for (int c = 0; c < NCHUNK; ++c) {
    const int kbase = ks * KSEC + c * KC;
    __syncthreads();
    // stage codebook chunk: 1024 uint4 via 16 wave-segments of 64 lanes
#pragma unroll
    for (int i = 0; i < 4; ++i) {
      int seg = i * 4 + wid;
      async_ld16(lB + seg * 1024, cbb16 + kbase * 8 + seg * 64 + lane);
    }
    if (t < 32) ((float4*)lN)[t] = ((const float4*)(norm2 + kbase))[t];
    __syncthreads();   // drains vmcnt(0): global_load_lds complete

#pragma unroll
    for (int nt = 0; nt < 8; ++nt) {
      int rb = nt * 16 + l15;
      const char* rowp = lB + rb * 128;
      short8 b0 = *(const short8*)(rowp + ((q     ) ^ (rb & 7)) * 16);
      short8 b1 = *(const short8*)(rowp + ((q + 4) ^ (rb & 7)) * 16);
      float n2 = lN[rb];
      unsigned kv = (unsigned)(kbase + rb);
#pragma unroll
      for (int mt = 0; mt < 2; ++mt) {
        f32x4 acc = {0.f, 0.f, 0.f, 0.f};
        acc = __builtin_amdgcn_mfma_f32_16x16x32_bf16(afr[mt][0], b0, acc, 0, 0, 0);
        acc = __builtin_amdgcn_mfma_f32_16x16x32_bf16(afr[mt][1], b1, acc, 0, 0, 0);
#pragma unroll
        for (int r = 0; r < 4; ++r) {
          // score = norm - 2*dot, affine-mapped into (0.5,1): s = (0.75+32n) - 64*acc
          float s = fmaf(acc[r], -64.f, n2);
          unsigned p = (__float_as_uint(s) & 0xFFFFE000u) | kv;
          rmin[mt][r] = p < rmin[mt][r] ? p : rmin[mt][r];
        }
      }
    }
  }

  // reduce over the 16 lanes sharing each C-row
#pragma unroll
  for (int mt = 0; mt < 2; ++mt)
#pragma unroll
    for (int r = 0; r < 4; ++r) {
      unsigned v = rmin[mt][r];
      unsigned o;
      o = (unsigned)__shfl_xor((int)v, 1); v = o < v ? o : v;
      o = (unsigned)__shfl_xor((int)v, 2); v = o < v ? o : v;
      o = (unsigned)__shfl_xor((int)v, 4); v = o < v ? o : v;
      o = (unsigned)__shfl_xor((int)v, 8); v = o < v ? o : v;
      rmin[mt][r] = v;
    }
  if (l15 == 0) {
#pragma unroll
    for (int mt = 0; mt < 2; ++mt)
#pragma unroll
      for (int r = 0; r < 4; ++r)
        atomicMin(&run[row0 + wid * 32 + mt * 16 + q * 4 + r], rmin[mt][r]);
  }
}

// ---------------------------------------------------------------------------
// Kernel 3: gather codebook rows into output layout + per-block loss partial.
// NO same-address atomics (R1's 41us was the 2048-atomic storm on misc[]).
// 1024 blocks x 256 threads, 4 elements (consecutive xyz) per thread.
// ---------------------------------------------------------------------------
__global__ __launch_bounds__(256) void vq_gather_loss(
    const float* __restrict__ lat,
    const float* __restrict__ cb,
    const unsigned* __restrict__ run,
    float* __restrict__ out,
    float* __restrict__ partials)   // [1024]
{
  const int t = threadIdx.x;
  const int gid = blockIdx.x * 256 + t;
  const int E0 = gid * 4;
  const int xyz = E0 & 4095;
  const int d = (E0 >> 12) & 63;
  const int b = E0 >> 18;
  const int n0 = b * 4096 + xyz;

  float4 l4 = *(const float4*)(lat + E0);
  uint4 i4 = *(const uint4*)(run + n0);
  float q0 = cb[(i4.x & 8191u) * 64 + d];
  float q1 = cb[(i4.y & 8191u) * 64 + d];
  float q2 = cb[(i4.z & 8191u) * 64 + d];
  float q3 = cb[(i4.w & 8191u) * 64 + d];
  *(float4*)(out + E0) = make_float4(q0, q1, q2, q3);

  float d0 = q0 - l4.x, d1 = q1 - l4.y, d2 = q2 - l4.z, d3 = q3 - l4.w;
  float dsum = d0 * d0 + d1 * d1 + d2 * d2 + d3 * d3;
#pragma unroll
  for (int m = 1; m < 64; m <<= 1) dsum += __shfl_xor(dsum, m);

  __shared__ float wsum[4];
  if ((t & 63) == 0) wsum[t >> 6] = dsum;
  __syncthreads();
  if (t == 0) partials[blockIdx.x] = wsum[0] + wsum[1] + wsum[2] + wsum[3];
}

// ---------------------------------------------------------------------------
// Kernel 4: final loss reduction (single block, no atomics).
// ---------------------------------------------------------------------------
__global__ __launch_bounds__(256) void vq_final(
    const float* __restrict__ partials,
    const float* __restrict__ vqw,
    float* __restrict__ out)
{
  const int t = threadIdx.x;
  float4 v = ((const float4*)partials)[t];
  float s = v.x + v.y + v.z + v.w;
#pragma unroll
  for (int m = 1; m < 64; m <<= 1) s += __shfl_xor(s, m);
  __shared__ float wsum[4];
  if ((t & 63) == 0) wsum[t >> 6] = s;
  __syncthreads();
  if (t == 0) {
    float total = wsum[0] + wsum[1] + wsum[2] + wsum[3];
    out[NROWS * 64] = total * (1.f + vqw[0]) / (float)(NROWS * 64);
  }
}

// ---------------------------------------------------------------------------
extern "C" void kernel_launch(void* const* d_in, const int* in_sizes, int n_in,
                              void* d_out, int out_size, void* d_ws, size_t ws_size,
                              hipStream_t stream) {
  const float* lat = (const float*)d_in[0];
  const float* vqw = (const float*)d_in[1];
  const float* cb  = (const float*)d_in[2];
  float* out = (float*)d_out;

  unsigned* ws    = (unsigned*)d_ws;
  uint4*    cbb16 = (uint4*)ws;                            // 65536 uint4 (1 MB)
  float*    norm2 = (float*)(ws + 262144);                 // 8192 floats
  unsigned* run   = ws + 262144 + 8192;                    // 16384 uints
  float*    partials = (float*)(ws + 262144 + 8192 + 16384); // 1024 floats

  vq_prep<<<256, 256, 0, stream>>>(cb, cbb16, norm2, run);
  vq_gemm<<<128 * KSPLIT, 256, 0, stream>>>(lat, cbb16, norm2, run);
  vq_gather_loss<<<1024, 256, 0, stream>>>(lat, cb, run, out, partials);
  vq_final<<<1, 256, 0, stream>>>(partials, vqw, out);
}